// Round 11
// baseline (182.037 us; speedup 1.0000x reference)
//
#include <hip/hip_runtime.h>
#include <hip/hip_bf16.h>

// Problem constants
#define S_LEN 4096
#define EMB   1024
#define NH    16
#define HD    64
#define WIN   256
#define SCALE 0.125f

typedef __attribute__((ext_vector_type(8))) short short8;          // 8 bf16
typedef __attribute__((ext_vector_type(4))) float f32x4;           // 4 fp32
typedef __attribute__((ext_vector_type(4))) unsigned short us4;    // 4 bf16

__device__ inline unsigned short f2b(float x) {
    __hip_bfloat16 b = __float2bfloat16(x);
    return *reinterpret_cast<unsigned short*>(&b);
}

__device__ inline void gld_lds16(const unsigned short* g, unsigned short* l) {
    __builtin_amdgcn_global_load_lds(
        (const __attribute__((address_space(1))) unsigned int*)g,
        (__attribute__((address_space(3))) unsigned int*)l,
        16, 0, 0);
}

// ---------------------------------------------------------------- fused prep
__device__ inline void transpose_tile(const float* __restrict__ in,
                                      unsigned short* __restrict__ out,
                                      int R, int C, int bx, int by,
                                      unsigned short* t) {
    const int tid = threadIdx.x;
    const int r0 = by * 64, c0 = bx * 64;

    const int rr = tid >> 4, cc = (tid & 15) * 4;
    #pragma unroll
    for (int i = 0; i < 4; ++i) {
        float4 v = *reinterpret_cast<const float4*>(&in[(size_t)(r0 + rr + i * 16) * C + c0 + cc]);
        t[(cc + 0) * 72 + rr + i * 16] = f2b(v.x);
        t[(cc + 1) * 72 + rr + i * 16] = f2b(v.y);
        t[(cc + 2) * 72 + rr + i * 16] = f2b(v.z);
        t[(cc + 3) * 72 + rr + i * 16] = f2b(v.w);
    }
    __syncthreads();

    const int wr = tid >> 2, wk = (tid & 3) * 16;
    #pragma unroll
    for (int p = 0; p < 2; ++p)
        *reinterpret_cast<uint4*>(&out[(size_t)(c0 + wr) * R + r0 + wk + p * 8]) =
            *reinterpret_cast<const uint4*>(&t[wr * 72 + wk + p * 8]);
}

__global__ __launch_bounds__(256) void prep(const float* __restrict__ x,
                                            unsigned short* __restrict__ xb,
                                            const float* __restrict__ w_qkv,
                                            unsigned short* __restrict__ wqkvT,
                                            const float* __restrict__ w_out,
                                            unsigned short* __restrict__ woutT) {
    __shared__ alignas(16) unsigned short t[64 * 72];
    const int b = blockIdx.x;
    if (b < 768) {
        transpose_tile(w_qkv, wqkvT, EMB, 3 * EMB, b % 48, b / 48, t);
    } else if (b < 1024) {
        const int bb = b - 768;
        transpose_tile(w_out, woutT, EMB, EMB, bb & 15, bb >> 4, t);
    } else {
        const size_t tt = (size_t)(b - 1024) * 256 + threadIdx.x;
        const float4* s4 = reinterpret_cast<const float4*>(x) + tt * 4;
        float4 v0 = s4[0], v1 = s4[1], v2 = s4[2], v3 = s4[3];
        us4 p0 = {f2b(v0.x), f2b(v0.y), f2b(v0.z), f2b(v0.w)};
        us4 p1 = {f2b(v1.x), f2b(v1.y), f2b(v1.z), f2b(v1.w)};
        us4 p2 = {f2b(v2.x), f2b(v2.y), f2b(v2.z), f2b(v2.w)};
        us4 p3 = {f2b(v3.x), f2b(v3.y), f2b(v3.z), f2b(v3.w)};
        us4* d = reinterpret_cast<us4*>(xb) + tt * 4;
        d[0] = p0; d[1] = p1; d[2] = p2; d[3] = p3;
    }
}

// ---------------------------------------------------------------- swizzled-DMA GEMM (out-proj, MODE 0)
template <int MODE, int BN>
__global__ __launch_bounds__(256) void gemm_bt(const unsigned short* __restrict__ A,
                                               const unsigned short* __restrict__ Bt,
                                               void* __restrict__ Cout,
                                               unsigned short* __restrict__ vT,
                                               int M, int N, int K) {
    constexpr int SMEM_ELEMS = (MODE == 1) ? 17408 : 8192 + BN * 64;
    constexpr int NJ = BN / 32;
    __shared__ alignas(16) unsigned short smem[SMEM_ELEMS];
    unsigned short* As = smem;           // [128][64] swizzled
    unsigned short* Bs = smem + 8192;    // [BN][64] swizzled

    const int tid  = threadIdx.x;
    const int lane = tid & 63;
    const int w    = tid >> 6;
    const int quad = lane >> 4;
    const int l16  = lane & 15;

    const int m0 = blockIdx.y * 128;
    const int n0 = blockIdx.x * BN;
    const int m_off = (w & 1) * 64;
    const int n_off = (w >> 1) * (BN / 2);

    const int s_row = tid >> 3;
    const int s_c0  = tid & 7;

    f32x4 acc[4][NJ];
    #pragma unroll
    for (int i = 0; i < 4; ++i)
        #pragma unroll
        for (int j = 0; j < NJ; ++j)
            acc[i][j] = (f32x4){0.f, 0.f, 0.f, 0.f};

    for (int bk = 0; bk < K; bk += 64) {
        __syncthreads();
        #pragma unroll
        for (int p = 0; p < 4; ++p) {
            const int row = p * 32 + s_row;
            const int c   = s_c0 ^ (row & 7);
            gld_lds16(A + (size_t)(m0 + row) * K + bk + c * 8,
                      As + (p * 256 + w * 64) * 8);
        }
        #pragma unroll
        for (int p = 0; p < BN / 32; ++p) {
            const int row = p * 32 + s_row;
            const int c   = s_c0 ^ (row & 7);
            gld_lds16(Bt + (size_t)(n0 + row) * K + bk + c * 8,
                      Bs + (p * 256 + w * 64) * 8);
        }
        __syncthreads();

        #pragma unroll
        for (int ks = 0; ks < 2; ++ks) {
            short8 af[4], bf[NJ];
            #pragma unroll
            for (int i = 0; i < 4; ++i) {
                const int r = m_off + i * 16 + l16;
                af[i] = *reinterpret_cast<const short8*>(
                    &As[r * 64 + ((ks * 4 + quad) ^ (r & 7)) * 8]);
            }
            #pragma unroll
            for (int j = 0; j < NJ; ++j) {
                const int r = n_off + j * 16 + l16;
                bf[j] = *reinterpret_cast<const short8*>(
                    &Bs[r * 64 + ((ks * 4 + quad) ^ (r & 7)) * 8]);
            }
            #pragma unroll
            for (int i = 0; i < 4; ++i)
                #pragma unroll
                for (int j = 0; j < NJ; ++j)
                    acc[i][j] = __builtin_amdgcn_mfma_f32_16x16x32_bf16(
                        af[i], bf[j], acc[i][j], 0, 0, 0);
        }
    }

    if (MODE == 0) {
        float* C = (float*)Cout;
        #pragma unroll
        for (int i = 0; i < 4; ++i)
            #pragma unroll
            for (int r = 0; r < 4; ++r) {
                const size_t row = m0 + m_off + i * 16 + quad * 4 + r;
                #pragma unroll
                for (int j = 0; j < NJ; ++j)
                    C[row * N + n0 + n_off + j * 16 + l16] = acc[i][j][r];
            }
    } else if (n0 < 2048) {
        const float sc = (n0 < 1024) ? SCALE : 1.0f;
        unsigned short* C = (unsigned short*)Cout;
        #pragma unroll
        for (int i = 0; i < 4; ++i)
            #pragma unroll
            for (int r = 0; r < 4; ++r) {
                const size_t row = m0 + m_off + i * 16 + quad * 4 + r;
                #pragma unroll
                for (int j = 0; j < NJ; ++j)
                    C[row * N + n0 + n_off + j * 16 + l16] = f2b(acc[i][j][r] * sc);
            }
    } else {
        __syncthreads();
        #pragma unroll
        for (int i = 0; i < 4; ++i) {
            const int ss = m_off + i * 16 + quad * 4;
            #pragma unroll
            for (int j = 0; j < NJ; ++j) {
                const int dd = n_off + j * 16 + l16;
                us4 pk = {f2b(acc[i][j][0]), f2b(acc[i][j][1]),
                          f2b(acc[i][j][2]), f2b(acc[i][j][3])};
                *reinterpret_cast<us4*>(&smem[dd * 136 + ss]) = pk;
            }
        }
        __syncthreads();
        #pragma unroll
        for (int p = 0; p < 8; ++p) {
            const int t  = p * 256 + tid;
            const int dd = t >> 4;
            const int sc2 = (t & 15) * 8;
            *reinterpret_cast<uint4*>(&vT[(size_t)(n0 - 2048 + dd) * S_LEN + m0 + sc2]) =
                *reinterpret_cast<const uint4*>(&smem[dd * 136 + sc2]);
        }
    }
}

// ---------------------------------------------------------------- QKV GEMM (R11): 256x192 tiles, 256 blocks = 1/CU balanced
// The one variable no prior variant changed: grid fill. 256x256 tiles gave
// 192 blocks on 256 CUs (25% idle, no co-residency to fill them). 256x192
// tiles give 16x16 = 256 blocks, exactly 1/CU. 16 waves (4x4) of 64x48,
// acc[4][3]=48 VGPR (~110 total < 128 cliff -> 4 waves/SIMD). LDS: 2-region
// ring x (A 16KB + B 12KB) = 56KB static. Ring-2 needs vmcnt(0)/phase, but
// phase DS work (112 ds_read_b128 ~ 1340cyc) > HBM latency (~900cyc) of the
// 2-load stage issued at phase start -> drain ~free. 192-wide tiles are not
// section-aligned: every 16-col j-group lies wholly in one section (16|1024),
// so Q/K store per-group with per-group scale; V groups go through a
// 64-d-chunked LDS transpose (64 x 264-padded, <=34KB, ring space reused
// after the final barrier; block-uniform branches). B staging = 768 chunks
// over 1024 threads: threads 768-1023 issue benign duplicate loads (same
// src -> same dst) keeping per-thread vmcnt uniform.
__global__ __launch_bounds__(1024, 4) void gemm_qkv(const unsigned short* __restrict__ A,
                                                    const unsigned short* __restrict__ Bt,
                                                    unsigned short* __restrict__ C,
                                                    unsigned short* __restrict__ vT) {
    __shared__ alignas(16) unsigned short smem[28672];   // 2 x 14336 elems = 56 KiB

    constexpr int K = EMB;       // 1024
    const int tid  = threadIdx.x;
    const int lane = tid & 63;
    const int w    = tid >> 6;          // 0..15
    const int quad = lane >> 4;
    const int l16  = lane & 15;
    const int wr   = w >> 2, wc = w & 3;
    const int wm0  = wr * 64, wn0 = wc * 48;

    // 256 blocks: 16m x 16n, XCD-chunked swizzle (256 % 8 == 0 -> bijective)
    const int raw = blockIdx.x;
    const int s   = (raw & 7) * 32 + (raw >> 3);
    const int by  = s >> 4, bx = s & 15;
    const int m0  = by * 256, n0 = bx * 192;

    // staging: A 1024 chunks -> 1/thread; B 768 chunks -> tid<768 (+dup rows 0..63)
    const int srowA = tid >> 2;
    const int scp   = tid & 3;
    const int scA   = scp ^ ((srowA >> 1) & 3);
    const int tB    = (tid < 768) ? tid : (tid - 768);
    const int srowB = tB >> 2;
    const int scB   = scp ^ ((srowB >> 1) & 3);
    const unsigned short* pA = A  + (size_t)(m0 + srowA) * K + scA * 8;
    const unsigned short* pB = Bt + (size_t)(n0 + srowB) * K + scB * 8;
    const int wB   = (w < 12) ? w : (w - 12);
    const int dlsA = w * 512;                 // wave-uniform LDS dest (elems)
    const int dlsB = 8192 + wB * 512;

    auto STAGE = [&](int q) {
        unsigned short* base = smem + (q & 1) * 14336;
        const int gk = q * 32;
        gld_lds16(pA + gk, base + dlsA);
        gld_lds16(pB + gk, base + dlsB);
    };

    const int cpf = quad ^ ((l16 >> 1) & 3);
    const int oA  = (wm0 + l16) * 32 + cpf * 8;           // + i*512
    const int oB  = 8192 + (wn0 + l16) * 32 + cpf * 8;    // + j*512

    f32x4 acc[4][3];
    #pragma unroll
    for (int i = 0; i < 4; ++i)
        #pragma unroll
        for (int j = 0; j < 3; ++j)
            acc[i][j] = (f32x4){0.f, 0.f, 0.f, 0.f};

    STAGE(0);
    asm volatile("s_waitcnt vmcnt(0)" ::: "memory");
    __builtin_amdgcn_s_barrier();

    for (int p = 0; p < 32; ++p) {
        const unsigned short* Rb = smem + (p & 1) * 14336;
        short8 af[4], bf[3];
        #pragma unroll
        for (int i = 0; i < 4; ++i)
            af[i] = *reinterpret_cast<const short8*>(&Rb[oA + i * 512]);
        #pragma unroll
        for (int j = 0; j < 3; ++j)
            bf[j] = *reinterpret_cast<const short8*>(&Rb[oB + j * 512]);
        if (p < 31) STAGE(p + 1);
        __builtin_amdgcn_s_setprio(1);
        #pragma unroll
        for (int i = 0; i < 4; ++i)
            #pragma unroll
            for (int j = 0; j < 3; ++j)
                acc[i][j] = __builtin_amdgcn_mfma_f32_16x16x32_bf16(af[i], bf[j], acc[i][j], 0, 0, 0);
        __builtin_amdgcn_s_setprio(0);
        asm volatile("s_waitcnt vmcnt(0)" ::: "memory");
        __builtin_amdgcn_s_barrier();
    }

    // ---- epilogue: per-16-col-group section handling (16 | 1024)
    #pragma unroll
    for (int j = 0; j < 3; ++j) {
        const int col16 = n0 + wn0 + j * 16;
        if (col16 < 2048) {
            const float sc = (col16 < 1024) ? SCALE : 1.0f;
            #pragma unroll
            for (int i = 0; i < 4; ++i)
                #pragma unroll
                for (int r = 0; r < 4; ++r)
                    C[(size_t)(m0 + wm0 + i * 16 + quad * 4 + r) * 3072 + col16 + l16] =
                        f2b(acc[i][j][r] * sc);
        }
    }
    if (n0 + 191 >= 2048) {
        const int vlo = (n0 >= 2048) ? 0 : (2048 - n0);   // 0 or 128 (bx==10)
        for (int dbase = vlo; dbase < 192; dbase += 64) {
            __builtin_amdgcn_s_barrier();
            #pragma unroll
            for (int j = 0; j < 3; ++j) {
                const int dcol = wn0 + j * 16;            // tile-relative column
                if (dcol >= dbase && dcol < dbase + 64) {
                    const int dr = dcol - dbase + l16;    // 0..63
                    #pragma unroll
                    for (int i = 0; i < 4; ++i) {
                        us4 pk = {f2b(acc[i][j][0]), f2b(acc[i][j][1]),
                                  f2b(acc[i][j][2]), f2b(acc[i][j][3])};
                        *reinterpret_cast<us4*>(&smem[dr * 264 + wm0 + i * 16 + quad * 4]) = pk;
                    }
                }
            }
            __builtin_amdgcn_s_barrier();
            #pragma unroll
            for (int rep = 0; rep < 2; ++rep) {
                const int idx = rep * 1024 + tid;
                const int drr = idx >> 5, ch = idx & 31;
                *reinterpret_cast<uint4*>(&vT[(size_t)(n0 + dbase + drr - 2048) * S_LEN + m0 + ch * 8]) =
                    *reinterpret_cast<const uint4*>(&smem[drr * 264 + ch * 8]);
            }
        }
    }
}

// ---------------------------------------------------------------- flash MFMA attention (v5, R8-proven)
typedef __attribute__((ext_vector_type(2))) unsigned int u32x2;

template <int PAR>
__device__ __forceinline__ void pv_phase(const u32x2 (&PA)[17], unsigned short* scrw,
                                         const unsigned short* Vt, f32x4 (&acco)[4],
                                         int ks0, int quad, int l16, short8 af) {
    const int wq  = quad & 1;
    const int tlq = quad >> 1;
    #pragma unroll
    for (int ksi = 0; ksi < 9; ++ksi) {
        if (ksi == 2) { asm volatile("s_waitcnt vmcnt(5)" ::: "memory"); __builtin_amdgcn_s_barrier(); }
        if (ksi == 4) { asm volatile("s_waitcnt vmcnt(3)" ::: "memory"); __builtin_amdgcn_s_barrier(); }
        if (ksi == 6) { asm volatile("s_waitcnt vmcnt(1)" ::: "memory"); __builtin_amdgcn_s_barrier(); }
        if (ksi == 8) { asm volatile("s_waitcnt vmcnt(0)" ::: "memory"); __builtin_amdgcn_s_barrier(); }
        const int ks = ks0 + ksi;
        if (ksi < 8) {
            #pragma unroll
            for (int tl = 0; tl < 2; ++tl) {
                const int nb = 2 * (ksi + 1) + tl - PAR;       // compile-time
                u32x2 v = (nb >= 0 && nb <= 16) ? PA[(nb < 0) ? 0 : ((nb > 16) ? 16 : nb)]
                                                : (u32x2){0u, 0u};
                *reinterpret_cast<u32x2*>(&scrw[((ksi + 1) & 1) * 768 + tl * 384 + l16 * 24 + quad * 4]) = v;
            }
        }
        #pragma unroll
        for (int nb2 = 0; nb2 < 4; ++nb2) {
            const int d = nb2 * 16 + l16;
            const short8 bfr = *reinterpret_cast<const short8*>(
                &Vt[ks * 2048 + d * 32 + ((quad ^ ((d >> 1) & 3)) << 3)]);
            acco[nb2] = __builtin_amdgcn_mfma_f32_16x16x32_bf16(af, bfr, acco[nb2], 0, 0, 0);
        }
        if (ksi < 8)
            af = *reinterpret_cast<const short8*>(&scrw[((ksi + 1) & 1) * 768 + tlq * 384 + l16 * 24 + wq * 8]);
    }
}

__global__ __launch_bounds__(256, 3) void attn_mfma(const unsigned short* __restrict__ qkv,
                                                    const unsigned short* __restrict__ vT,
                                                    unsigned short* __restrict__ outb) {
    __shared__ alignas(16) unsigned short lds[26624];   // 53248 B
    unsigned short* KtV = lds;              // phase 1: Kt [320][64] sw; phase 2: Vt [10][64][4] group-major
    unsigned short* scr = lds + 20480;      // 4 waves x 2 slots x 2 tl x 16 q x 24 (pad)

    const int raw  = blockIdx.x + (blockIdx.y << 6);   // gridDim = (64,16)
    const int xcd  = raw & 7;
    const int slot = raw >> 3;
    const int q0   = (xcd * 8 + (slot & 7)) * 64;
    const int h    = slot >> 3;

    const int tid  = threadIdx.x;
    const int w    = tid >> 6;
    const int lane = tid & 63;
    const int quad = lane >> 4;
    const int l16  = lane & 15;
    const int kbase = q0 - 256;

    // ---- Q fragment loads first (plain VMEM, overlap with DMA issue)
    const unsigned short* qrow = qkv + (size_t)(q0 + w * 16 + l16) * 3072 + h * 64;
    short8 aq[2];
    aq[0] = *reinterpret_cast<const short8*>(qrow + quad * 8);
    aq[1] = *reinterpret_cast<const short8*>(qrow + 32 + quad * 8);

    // ---- K DMA (clamped source row; masked rows never contribute)
    #pragma unroll
    for (int i = 0; i < 10; ++i) {
        const int fc  = i * 256 + tid;
        const int row = fc >> 3, p = fc & 7;
        const int c   = p ^ (row & 7);
        int j = kbase + row; if (j < 0) j = 0;
        gld_lds16(qkv + (size_t)j * 3072 + EMB + h * 64 + c * 8,
                  KtV + (i * 256 + w * 64) * 8);
    }

    __syncthreads();   // drains K (+ Q)

    // ---- swapped QK^T with fused per-tile softmax (lane l16 = own query)
    const int iq = q0 + w * 16 + l16;
    float rsum = 0.f;
    u32x2 PA[17];
    #pragma unroll
    for (int nb = 0; nb < 17; ++nb) {
        const int row = (w + nb) * 16 + l16;
        f32x4 acc = (f32x4){0.f, 0.f, 0.f, 0.f};
        #pragma unroll
        for (int ks = 0; ks < 2; ++ks) {
            const int p = (ks * 4 + quad) ^ (l16 & 7);
            const short8 kf = *reinterpret_cast<const short8*>(&KtV[row * 64 + p * 8]);
            acc = __builtin_amdgcn_mfma_f32_16x16x32_bf16(kf, aq[ks], acc, 0, 0, 0);
        }
        const int jb = kbase + (w + nb) * 16 + quad * 4;
        float ev0, ev1, ev2, ev3;
        {
            const int j0 = jb, j1 = jb + 1, j2 = jb + 2, j3 = jb + 3;
            ev0 = ((j0 >= 0) & (j0 <= iq) & (j0 > iq - WIN)) ? __expf(acc[0]) : 0.f;
            ev1 = ((j1 >= 0) & (j1 <= iq) & (j1 > iq - WIN)) ? __expf(acc[1]) : 0.f;
            ev2 = ((j2 >= 0) & (j2 <= iq) & (j2 > iq - WIN)) ? __expf(acc[2]) : 0.f;
            ev3 = ((j3 >= 0) & (j3 <= iq) & (j3 > iq - WIN)) ? __expf(acc[3]) : 0.f;
        }
        rsum += (ev0 + ev1) + (ev2 + ev3);
        PA[nb][0] = ((unsigned)f2b(ev1) << 16) | f2b(ev0);
        PA[nb][1] = ((unsigned)f2b(ev3) << 16) | f2b(ev2);
    }
    rsum += __shfl_xor(rsum, 16, 64);
    rsum += __shfl_xor(rsum, 32, 64);
    const float inv_l = 1.f / rsum;

    __syncthreads();   // all Kt reads done -> region becomes Vt

    // ---- V DMA, group-major: group i = 16B chunk-cols [4i,4i+4) of all 64 d-rows
    {
        const int vd  = tid >> 2;                       // d row 0..63
        const int vpo = tid & 3;                        // stored slot
        const int vsw = vpo ^ ((vd >> 1) & 3);          // global chunk low bits
        const unsigned short* vsrc = vT + (size_t)(h * 64 + vd) * S_LEN;
        #pragma unroll
        for (int i = 0; i < 10; ++i) {
            int j0 = kbase + (4 * i + vsw) * 8; if (j0 < 0) j0 = 0;
            gld_lds16(vsrc + j0, KtV + (i * 256 + w * 64) * 8);
        }
    }

    // ---- step-0 A-frag exchange under the V DMA (wave-private scratch, lgkm only)
    unsigned short* scrw = scr + w * 1536;
    const int par = w & 1;
    {
        const u32x2 z = {0u, 0u};
        u32x2 v0 = par ? z : PA[0];
        u32x2 v1 = par ? PA[0] : PA[1];
        *reinterpret_cast<u32x2*>(&scrw[0 * 384 + l16 * 24 + quad * 4]) = v0;
        *reinterpret_cast<u32x2*>(&scrw[1 * 384 + l16 * 24 + quad * 4]) = v1;
    }
    const short8 af0 = *reinterpret_cast<const short8*>(
        &scrw[(quad >> 1) * 384 + l16 * 24 + (quad & 1) * 8]);

    // ---- entry drain: groups 0..2 landed (covers PV ksi 0,1); rest drain in-loop
    asm volatile("s_waitcnt vmcnt(7)" ::: "memory");
    __builtin_amdgcn_s_barrier();

    // ---- PV: O[16 q][64 d] per wave; 9 k-steps; staged V drains inside
    f32x4 acco[4];
    #pragma unroll
    for (int nb2 = 0; nb2 < 4; ++nb2) acco[nb2] = (f32x4){0.f, 0.f, 0.f, 0.f};

    const int ks0 = w >> 1;
    if (par == 0) pv_phase<0>(PA, scrw, KtV, acco, ks0, quad, l16, af0);
    else          pv_phase<1>(PA, scrw, KtV, acco, ks0, quad, l16, af0);

    // ---- epilogue
    float invo[4];
    #pragma unroll
    for (int r = 0; r < 4; ++r)
        invo[r] = __shfl(inv_l, quad * 4 + r, 64);

    #pragma unroll
    for (int nb2 = 0; nb2 < 4; ++nb2)
        #pragma unroll
        for (int r = 0; r < 4; ++r)
            outb[(size_t)(q0 + w * 16 + quad * 4 + r) * EMB + h * 64 + nb2 * 16 + l16] =
                f2b(acco[nb2][r] * invo[r]);
}

// ---------------------------------------------------------------- launch
extern "C" void kernel_launch(void* const* d_in, const int* in_sizes, int n_in,
                              void* d_out, int out_size, void* d_ws, size_t ws_size,
                              hipStream_t stream) {
    const float* x     = (const float*)d_in[0];
    const float* w_qkv = (const float*)d_in[2];
    const float* w_out = (const float*)d_in[3];
    float* out = (float*)d_out;

    char* ws = (char*)d_ws;
    unsigned short* xb     = (unsigned short*)(ws);                 // [4096][1024] bf16
    unsigned short* wqkvT  = (unsigned short*)(ws + (8u  << 20));   // [3072][1024] bf16
    unsigned short* woutT  = (unsigned short*)(ws + (14u << 20));   // [1024][1024] bf16
    unsigned short* qkvb   = (unsigned short*)(ws + (16u << 20));   // [4096][3072] (Q,K; Q prescaled)
    unsigned short* attnb  = (unsigned short*)(ws + (48u << 20));   // [4096][1024] bf16
    unsigned short* vT     = (unsigned short*)(ws + (56u << 20));   // [1024][4096] bf16

    prep<<<2048, 256, 0, stream>>>(x, xb, w_qkv, wqkvT, w_out, woutT);

    // qkv = x @ w_qkv ; Q (prescaled), K -> qkvb bf16, V -> vT transposed
    gemm_qkv<<<dim3(256), 1024, 0, stream>>>(xb, wqkvT, qkvb, vT);

    attn_mfma<<<dim3(S_LEN / 64, NH), 256, 0, stream>>>(qkvb, vT, attnb);

    // out = attn @ w_out -> f32 (BN=64: 512 blocks = 2/CU)
    gemm_bt<0, 64><<<dim3(EMB / 64, S_LEN / 128), 256, 0, stream>>>(
        attnb, woutT, out, nullptr, S_LEN, EMB, EMB);
}

// Round 12
// 180.523 us; speedup vs baseline: 1.0084x; 1.0084x over previous
//
#include <hip/hip_runtime.h>
#include <hip/hip_bf16.h>

// Problem constants
#define S_LEN 4096
#define EMB   1024
#define NH    16
#define HD    64
#define WIN   256
#define SCALE 0.125f

typedef __attribute__((ext_vector_type(8))) short short8;          // 8 bf16
typedef __attribute__((ext_vector_type(4))) float f32x4;           // 4 fp32
typedef __attribute__((ext_vector_type(4))) unsigned short us4;    // 4 bf16

__device__ inline unsigned short f2b(float x) {
    __hip_bfloat16 b = __float2bfloat16(x);
    return *reinterpret_cast<unsigned short*>(&b);
}

__device__ inline void gld_lds16(const unsigned short* g, unsigned short* l) {
    __builtin_amdgcn_global_load_lds(
        (const __attribute__((address_space(1))) unsigned int*)g,
        (__attribute__((address_space(3))) unsigned int*)l,
        16, 0, 0);
}

// ---------------------------------------------------------------- fused prep
__device__ inline void transpose_tile(const float* __restrict__ in,
                                      unsigned short* __restrict__ out,
                                      int R, int C, int bx, int by,
                                      unsigned short* t) {
    const int tid = threadIdx.x;
    const int r0 = by * 64, c0 = bx * 64;

    const int rr = tid >> 4, cc = (tid & 15) * 4;
    #pragma unroll
    for (int i = 0; i < 4; ++i) {
        float4 v = *reinterpret_cast<const float4*>(&in[(size_t)(r0 + rr + i * 16) * C + c0 + cc]);
        t[(cc + 0) * 72 + rr + i * 16] = f2b(v.x);
        t[(cc + 1) * 72 + rr + i * 16] = f2b(v.y);
        t[(cc + 2) * 72 + rr + i * 16] = f2b(v.z);
        t[(cc + 3) * 72 + rr + i * 16] = f2b(v.w);
    }
    __syncthreads();

    const int wr = tid >> 2, wk = (tid & 3) * 16;
    #pragma unroll
    for (int p = 0; p < 2; ++p)
        *reinterpret_cast<uint4*>(&out[(size_t)(c0 + wr) * R + r0 + wk + p * 8]) =
            *reinterpret_cast<const uint4*>(&t[wr * 72 + wk + p * 8]);
}

__global__ __launch_bounds__(256) void prep(const float* __restrict__ x,
                                            unsigned short* __restrict__ xb,
                                            const float* __restrict__ w_qkv,
                                            unsigned short* __restrict__ wqkvT,
                                            const float* __restrict__ w_out,
                                            unsigned short* __restrict__ woutT) {
    __shared__ alignas(16) unsigned short t[64 * 72];
    const int b = blockIdx.x;
    if (b < 768) {
        transpose_tile(w_qkv, wqkvT, EMB, 3 * EMB, b % 48, b / 48, t);
    } else if (b < 1024) {
        const int bb = b - 768;
        transpose_tile(w_out, woutT, EMB, EMB, bb & 15, bb >> 4, t);
    } else {
        const size_t tt = (size_t)(b - 1024) * 256 + threadIdx.x;
        const float4* s4 = reinterpret_cast<const float4*>(x) + tt * 4;
        float4 v0 = s4[0], v1 = s4[1], v2 = s4[2], v3 = s4[3];
        us4 p0 = {f2b(v0.x), f2b(v0.y), f2b(v0.z), f2b(v0.w)};
        us4 p1 = {f2b(v1.x), f2b(v1.y), f2b(v1.z), f2b(v1.w)};
        us4 p2 = {f2b(v2.x), f2b(v2.y), f2b(v2.z), f2b(v2.w)};
        us4 p3 = {f2b(v3.x), f2b(v3.y), f2b(v3.z), f2b(v3.w)};
        us4* d = reinterpret_cast<us4*>(xb) + tt * 4;
        d[0] = p0; d[1] = p1; d[2] = p2; d[3] = p3;
    }
}

// ---------------------------------------------------------------- swizzled-DMA GEMM (out-proj, MODE 0)
template <int MODE, int BN>
__global__ __launch_bounds__(256) void gemm_bt(const unsigned short* __restrict__ A,
                                               const unsigned short* __restrict__ Bt,
                                               void* __restrict__ Cout,
                                               unsigned short* __restrict__ vT,
                                               int M, int N, int K) {
    constexpr int SMEM_ELEMS = (MODE == 1) ? 17408 : 8192 + BN * 64;
    constexpr int NJ = BN / 32;
    __shared__ alignas(16) unsigned short smem[SMEM_ELEMS];
    unsigned short* As = smem;           // [128][64] swizzled
    unsigned short* Bs = smem + 8192;    // [BN][64] swizzled

    const int tid  = threadIdx.x;
    const int lane = tid & 63;
    const int w    = tid >> 6;
    const int quad = lane >> 4;
    const int l16  = lane & 15;

    const int m0 = blockIdx.y * 128;
    const int n0 = blockIdx.x * BN;
    const int m_off = (w & 1) * 64;
    const int n_off = (w >> 1) * (BN / 2);

    const int s_row = tid >> 3;
    const int s_c0  = tid & 7;

    f32x4 acc[4][NJ];
    #pragma unroll
    for (int i = 0; i < 4; ++i)
        #pragma unroll
        for (int j = 0; j < NJ; ++j)
            acc[i][j] = (f32x4){0.f, 0.f, 0.f, 0.f};

    for (int bk = 0; bk < K; bk += 64) {
        __syncthreads();
        #pragma unroll
        for (int p = 0; p < 4; ++p) {
            const int row = p * 32 + s_row;
            const int c   = s_c0 ^ (row & 7);
            gld_lds16(A + (size_t)(m0 + row) * K + bk + c * 8,
                      As + (p * 256 + w * 64) * 8);
        }
        #pragma unroll
        for (int p = 0; p < BN / 32; ++p) {
            const int row = p * 32 + s_row;
            const int c   = s_c0 ^ (row & 7);
            gld_lds16(Bt + (size_t)(n0 + row) * K + bk + c * 8,
                      Bs + (p * 256 + w * 64) * 8);
        }
        __syncthreads();

        #pragma unroll
        for (int ks = 0; ks < 2; ++ks) {
            short8 af[4], bf[NJ];
            #pragma unroll
            for (int i = 0; i < 4; ++i) {
                const int r = m_off + i * 16 + l16;
                af[i] = *reinterpret_cast<const short8*>(
                    &As[r * 64 + ((ks * 4 + quad) ^ (r & 7)) * 8]);
            }
            #pragma unroll
            for (int j = 0; j < NJ; ++j) {
                const int r = n_off + j * 16 + l16;
                bf[j] = *reinterpret_cast<const short8*>(
                    &Bs[r * 64 + ((ks * 4 + quad) ^ (r & 7)) * 8]);
            }
            #pragma unroll
            for (int i = 0; i < 4; ++i)
                #pragma unroll
                for (int j = 0; j < NJ; ++j)
                    acc[i][j] = __builtin_amdgcn_mfma_f32_16x16x32_bf16(
                        af[i], bf[j], acc[i][j], 0, 0, 0);
        }
    }

    if (MODE == 0) {
        float* C = (float*)Cout;
        #pragma unroll
        for (int i = 0; i < 4; ++i)
            #pragma unroll
            for (int r = 0; r < 4; ++r) {
                const size_t row = m0 + m_off + i * 16 + quad * 4 + r;
                #pragma unroll
                for (int j = 0; j < NJ; ++j)
                    C[row * N + n0 + n_off + j * 16 + l16] = acc[i][j][r];
            }
    } else if (n0 < 2048) {
        const float sc = (n0 < 1024) ? SCALE : 1.0f;
        unsigned short* C = (unsigned short*)Cout;
        #pragma unroll
        for (int i = 0; i < 4; ++i)
            #pragma unroll
            for (int r = 0; r < 4; ++r) {
                const size_t row = m0 + m_off + i * 16 + quad * 4 + r;
                #pragma unroll
                for (int j = 0; j < NJ; ++j)
                    C[row * N + n0 + n_off + j * 16 + l16] = f2b(acc[i][j][r] * sc);
            }
    } else {
        __syncthreads();
        #pragma unroll
        for (int i = 0; i < 4; ++i) {
            const int ss = m_off + i * 16 + quad * 4;
            #pragma unroll
            for (int j = 0; j < NJ; ++j) {
                const int dd = n_off + j * 16 + l16;
                us4 pk = {f2b(acc[i][j][0]), f2b(acc[i][j][1]),
                          f2b(acc[i][j][2]), f2b(acc[i][j][3])};
                *reinterpret_cast<us4*>(&smem[dd * 136 + ss]) = pk;
            }
        }
        __syncthreads();
        #pragma unroll
        for (int p = 0; p < 8; ++p) {
            const int t  = p * 256 + tid;
            const int dd = t >> 4;
            const int sc2 = (t & 15) * 8;
            *reinterpret_cast<uint4*>(&vT[(size_t)(n0 - 2048 + dd) * S_LEN + m0 + sc2]) =
                *reinterpret_cast<const uint4*>(&smem[dd * 136 + sc2]);
        }
    }
}

// ---------------------------------------------------------------- QKV GEMM (R10-proven): 16 waves / 64x64 per wave
// 256x256 tile, 4-region BK=32 LDS ring (4 x 32KB = 128KB), chunk swizzle and
// counted-vmcnt discipline; 1024 threads -> per-wave output 64x64, acc[4][4]
// = 64 VGPR, 4 waves/SIMD (16/CU). Best-measured gemm_qkv variant (R10).
__global__ __launch_bounds__(1024, 4) void gemm_qkv(const unsigned short* __restrict__ A,
                                                    const unsigned short* __restrict__ Bt,
                                                    unsigned short* __restrict__ C,
                                                    unsigned short* __restrict__ vT) {
    __shared__ alignas(16) unsigned short smem[65536];   // 128 KiB

    constexpr int K = EMB;       // 1024
    const int tid  = threadIdx.x;
    const int lane = tid & 63;
    const int w    = tid >> 6;          // 0..15
    const int quad = lane >> 4;
    const int l16  = lane & 15;
    const int wr   = w >> 2, wc = w & 3;
    const int wm0  = wr * 64, wn0 = wc * 64;

    const int raw = blockIdx.x;
    const int s   = (raw & 7) * 24 + (raw >> 3);
    const int by  = s / 12, bx = s % 12;
    const int m0  = by * 256, n0 = bx * 256;

    // staging: thread covers row srow (0..255), chunk scp; swizzled source chunk
    const int srow = tid >> 2;
    const int scp  = tid & 3;
    const int sc4  = scp ^ ((srow >> 1) & 3);
    const unsigned short* pA = A  + (size_t)(m0 + srow) * K + sc4 * 8;
    const unsigned short* pB = Bt + (size_t)(n0 + srow) * K + sc4 * 8;
    const int dls = (w * 64) * 8;       // wave-uniform LDS dest (elems)

    auto STAGE = [&](int q) {
        unsigned short* dA = smem + (q & 3) * 16384 + dls;
        const int gk = q * 32;
        gld_lds16(pA + gk, dA);            // A half: 16 KB
        gld_lds16(pB + gk, dA + 8192);     // B half: 16 KB
    };

    const int cpf = quad ^ ((l16 >> 1) & 3);
    const int oA  = (wm0 + l16) * 32 + cpf * 8;   // + i*512 (16 rows)
    const int oB  = (wn0 + l16) * 32 + cpf * 8;   // + j*512

    f32x4 acc[4][4];
    #pragma unroll
    for (int i = 0; i < 4; ++i)
        #pragma unroll
        for (int j = 0; j < 4; ++j)
            acc[i][j] = (f32x4){0.f, 0.f, 0.f, 0.f};

#define QKV_PH(p, DO_ST, VM) do {                                              \
    const unsigned short* Ab_ = smem + ((p) & 3) * 16384;                      \
    const unsigned short* Bb_ = Ab_ + 8192;                                    \
    short8 af[4], bf[4];                                                       \
    _Pragma("unroll")                                                          \
    for (int i = 0; i < 4; ++i)                                                \
        af[i] = *reinterpret_cast<const short8*>(&Ab_[oA + i * 512]);          \
    _Pragma("unroll")                                                          \
    for (int j = 0; j < 4; ++j)                                                \
        bf[j] = *reinterpret_cast<const short8*>(&Bb_[oB + j * 512]);          \
    if (DO_ST) STAGE((p) + 3);                                                 \
    __builtin_amdgcn_s_setprio(1);                                             \
    _Pragma("unroll")                                                          \
    for (int i = 0; i < 4; ++i)                                                \
        _Pragma("unroll")                                                      \
        for (int j = 0; j < 4; ++j)                                            \
            acc[i][j] = __builtin_amdgcn_mfma_f32_16x16x32_bf16(               \
                af[i], bf[j], acc[i][j], 0, 0, 0);                             \
    __builtin_amdgcn_s_setprio(0);                                             \
    asm volatile("s_waitcnt " VM ::: "memory");                                \
    __builtin_amdgcn_s_barrier();                                              \
} while (0)

    // prologue: regions 0..2 staged (6 loads/thread); vmcnt(4) -> region 0 landed
    STAGE(0); STAGE(1); STAGE(2);
    asm volatile("s_waitcnt vmcnt(4)" ::: "memory");
    __builtin_amdgcn_s_barrier();

    for (int p = 0; p < 29; ++p)
        QKV_PH(p, true, "vmcnt(4)");       // stages p+3 (max 31)
    QKV_PH(29, false, "vmcnt(2)");         // outstanding 30,31 -> 30 landed
    QKV_PH(30, false, "vmcnt(0)");         // drain 31
    QKV_PH(31, false, "vmcnt(0)");         // free (already drained)
#undef QKV_PH

    const int sec = n0 >> 10;                 // 0=Q, 1=K, 2=V
    if (sec < 2) {
        const float sc = (sec == 0) ? SCALE : 1.0f;
        #pragma unroll
        for (int i = 0; i < 4; ++i) {
            #pragma unroll
            for (int r = 0; r < 4; ++r) {
                const size_t row = (size_t)(m0 + wm0 + i * 16 + quad * 4 + r) * 3072;
                #pragma unroll
                for (int j = 0; j < 4; ++j)
                    C[row + n0 + wn0 + j * 16 + l16] = f2b(acc[i][j][r] * sc);
            }
        }
    } else {
        // V: transpose 256x256 via LDS (chunk slot = sc0 ^ (d&31)), write vT[d][s]
        #pragma unroll
        for (int i = 0; i < 4; ++i) {
            const int ss = wm0 + i * 16 + quad * 4;
            const int sc0 = ss >> 3, se = ss & 7;
            #pragma unroll
            for (int j = 0; j < 4; ++j) {
                const int d = wn0 + j * 16 + l16;
                us4 pk = {f2b(acc[i][j][0]), f2b(acc[i][j][1]),
                          f2b(acc[i][j][2]), f2b(acc[i][j][3])};
                *reinterpret_cast<us4*>(&smem[d * 256 + ((sc0 ^ (d & 31)) << 3) + se]) = pk;
            }
        }
        __builtin_amdgcn_s_barrier();
        const int vb = n0 - 2048;
        #pragma unroll
        for (int rep = 0; rep < 8; ++rep) {
            const int idx = rep * 1024 + tid;
            const int d = idx >> 5, scr = idx & 31;
            *reinterpret_cast<uint4*>(&vT[(size_t)(vb + d) * S_LEN + m0 + scr * 8]) =
                *reinterpret_cast<const uint4*>(&smem[d * 256 + ((scr ^ (d & 31)) << 3)]);
        }
    }
}

// ---------------------------------------------------------------- flash MFMA attention (v5, R8/R10-proven)
typedef __attribute__((ext_vector_type(2))) unsigned int u32x2;

template <int PAR>
__device__ __forceinline__ void pv_phase(const u32x2 (&PA)[17], unsigned short* scrw,
                                         const unsigned short* Vt, f32x4 (&acco)[4],
                                         int ks0, int quad, int l16, short8 af) {
    const int wq  = quad & 1;
    const int tlq = quad >> 1;
    #pragma unroll
    for (int ksi = 0; ksi < 9; ++ksi) {
        if (ksi == 2) { asm volatile("s_waitcnt vmcnt(5)" ::: "memory"); __builtin_amdgcn_s_barrier(); }
        if (ksi == 4) { asm volatile("s_waitcnt vmcnt(3)" ::: "memory"); __builtin_amdgcn_s_barrier(); }
        if (ksi == 6) { asm volatile("s_waitcnt vmcnt(1)" ::: "memory"); __builtin_amdgcn_s_barrier(); }
        if (ksi == 8) { asm volatile("s_waitcnt vmcnt(0)" ::: "memory"); __builtin_amdgcn_s_barrier(); }
        const int ks = ks0 + ksi;
        if (ksi < 8) {
            #pragma unroll
            for (int tl = 0; tl < 2; ++tl) {
                const int nb = 2 * (ksi + 1) + tl - PAR;       // compile-time
                u32x2 v = (nb >= 0 && nb <= 16) ? PA[(nb < 0) ? 0 : ((nb > 16) ? 16 : nb)]
                                                : (u32x2){0u, 0u};
                *reinterpret_cast<u32x2*>(&scrw[((ksi + 1) & 1) * 768 + tl * 384 + l16 * 24 + quad * 4]) = v;
            }
        }
        #pragma unroll
        for (int nb2 = 0; nb2 < 4; ++nb2) {
            const int d = nb2 * 16 + l16;
            const short8 bfr = *reinterpret_cast<const short8*>(
                &Vt[ks * 2048 + d * 32 + ((quad ^ ((d >> 1) & 3)) << 3)]);
            acco[nb2] = __builtin_amdgcn_mfma_f32_16x16x32_bf16(af, bfr, acco[nb2], 0, 0, 0);
        }
        if (ksi < 8)
            af = *reinterpret_cast<const short8*>(&scrw[((ksi + 1) & 1) * 768 + tlq * 384 + l16 * 24 + wq * 8]);
    }
}

__global__ __launch_bounds__(256, 3) void attn_mfma(const unsigned short* __restrict__ qkv,
                                                    const unsigned short* __restrict__ vT,
                                                    unsigned short* __restrict__ outb) {
    __shared__ alignas(16) unsigned short lds[26624];   // 53248 B
    unsigned short* KtV = lds;              // phase 1: Kt [320][64] sw; phase 2: Vt [10][64][4] group-major
    unsigned short* scr = lds + 20480;      // 4 waves x 2 slots x 2 tl x 16 q x 24 (pad)

    const int raw  = blockIdx.x + (blockIdx.y << 6);   // gridDim = (64,16)
    const int xcd  = raw & 7;
    const int slot = raw >> 3;
    const int q0   = (xcd * 8 + (slot & 7)) * 64;
    const int h    = slot >> 3;

    const int tid  = threadIdx.x;
    const int w    = tid >> 6;
    const int lane = tid & 63;
    const int quad = lane >> 4;
    const int l16  = lane & 15;
    const int kbase = q0 - 256;

    // ---- Q fragment loads first (plain VMEM, overlap with DMA issue)
    const unsigned short* qrow = qkv + (size_t)(q0 + w * 16 + l16) * 3072 + h * 64;
    short8 aq[2];
    aq[0] = *reinterpret_cast<const short8*>(qrow + quad * 8);
    aq[1] = *reinterpret_cast<const short8*>(qrow + 32 + quad * 8);

    // ---- K DMA (clamped source row; masked rows never contribute)
    #pragma unroll
    for (int i = 0; i < 10; ++i) {
        const int fc  = i * 256 + tid;
        const int row = fc >> 3, p = fc & 7;
        const int c   = p ^ (row & 7);
        int j = kbase + row; if (j < 0) j = 0;
        gld_lds16(qkv + (size_t)j * 3072 + EMB + h * 64 + c * 8,
                  KtV + (i * 256 + w * 64) * 8);
    }

    __syncthreads();   // drains K (+ Q)

    // ---- swapped QK^T with fused per-tile softmax (lane l16 = own query)
    const int iq = q0 + w * 16 + l16;
    float rsum = 0.f;
    u32x2 PA[17];
    #pragma unroll
    for (int nb = 0; nb < 17; ++nb) {
        const int row = (w + nb) * 16 + l16;
        f32x4 acc = (f32x4){0.f, 0.f, 0.f, 0.f};
        #pragma unroll
        for (int ks = 0; ks < 2; ++ks) {
            const int p = (ks * 4 + quad) ^ (l16 & 7);
            const short8 kf = *reinterpret_cast<const short8*>(&KtV[row * 64 + p * 8]);
            acc = __builtin_amdgcn_mfma_f32_16x16x32_bf16(kf, aq[ks], acc, 0, 0, 0);
        }
        const int jb = kbase + (w + nb) * 16 + quad * 4;
        float ev0, ev1, ev2, ev3;
        {
            const int j0 = jb, j1 = jb + 1, j2 = jb + 2, j3 = jb + 3;
            ev0 = ((j0 >= 0) & (j0 <= iq) & (j0 > iq - WIN)) ? __expf(acc[0]) : 0.f;
            ev1 = ((j1 >= 0) & (j1 <= iq) & (j1 > iq - WIN)) ? __expf(acc[1]) : 0.f;
            ev2 = ((j2 >= 0) & (j2 <= iq) & (j2 > iq - WIN)) ? __expf(acc[2]) : 0.f;
            ev3 = ((j3 >= 0) & (j3 <= iq) & (j3 > iq - WIN)) ? __expf(acc[3]) : 0.f;
        }
        rsum += (ev0 + ev1) + (ev2 + ev3);
        PA[nb][0] = ((unsigned)f2b(ev1) << 16) | f2b(ev0);
        PA[nb][1] = ((unsigned)f2b(ev3) << 16) | f2b(ev2);
    }
    rsum += __shfl_xor(rsum, 16, 64);
    rsum += __shfl_xor(rsum, 32, 64);
    const float inv_l = 1.f / rsum;

    __syncthreads();   // all Kt reads done -> region becomes Vt

    // ---- V DMA, group-major: group i = 16B chunk-cols [4i,4i+4) of all 64 d-rows
    {
        const int vd  = tid >> 2;                       // d row 0..63
        const int vpo = tid & 3;                        // stored slot
        const int vsw = vpo ^ ((vd >> 1) & 3);          // global chunk low bits
        const unsigned short* vsrc = vT + (size_t)(h * 64 + vd) * S_LEN;
        #pragma unroll
        for (int i = 0; i < 10; ++i) {
            int j0 = kbase + (4 * i + vsw) * 8; if (j0 < 0) j0 = 0;
            gld_lds16(vsrc + j0, KtV + (i * 256 + w * 64) * 8);
        }
    }

    // ---- step-0 A-frag exchange under the V DMA (wave-private scratch, lgkm only)
    unsigned short* scrw = scr + w * 1536;
    const int par = w & 1;
    {
        const u32x2 z = {0u, 0u};
        u32x2 v0 = par ? z : PA[0];
        u32x2 v1 = par ? PA[0] : PA[1];
        *reinterpret_cast<u32x2*>(&scrw[0 * 384 + l16 * 24 + quad * 4]) = v0;
        *reinterpret_cast<u32x2*>(&scrw[1 * 384 + l16 * 24 + quad * 4]) = v1;
    }
    const short8 af0 = *reinterpret_cast<const short8*>(
        &scrw[(quad >> 1) * 384 + l16 * 24 + (quad & 1) * 8]);

    // ---- entry drain: groups 0..2 landed (covers PV ksi 0,1); rest drain in-loop
    asm volatile("s_waitcnt vmcnt(7)" ::: "memory");
    __builtin_amdgcn_s_barrier();

    // ---- PV: O[16 q][64 d] per wave; 9 k-steps; staged V drains inside
    f32x4 acco[4];
    #pragma unroll
    for (int nb2 = 0; nb2 < 4; ++nb2) acco[nb2] = (f32x4){0.f, 0.f, 0.f, 0.f};

    const int ks0 = w >> 1;
    if (par == 0) pv_phase<0>(PA, scrw, KtV, acco, ks0, quad, l16, af0);
    else          pv_phase<1>(PA, scrw, KtV, acco, ks0, quad, l16, af0);

    // ---- epilogue
    float invo[4];
    #pragma unroll
    for (int r = 0; r < 4; ++r)
        invo[r] = __shfl(inv_l, quad * 4 + r, 64);

    #pragma unroll
    for (int nb2 = 0; nb2 < 4; ++nb2)
        #pragma unroll
        for (int r = 0; r < 4; ++r)
            outb[(size_t)(q0 + w * 16 + quad * 4 + r) * EMB + h * 64 + nb2 * 16 + l16] =
                f2b(acco[nb2][r] * invo[r]);
}

// ---------------------------------------------------------------- launch
extern "C" void kernel_launch(void* const* d_in, const int* in_sizes, int n_in,
                              void* d_out, int out_size, void* d_ws, size_t ws_size,
                              hipStream_t stream) {
    const float* x     = (const float*)d_in[0];
    const float* w_qkv = (const float*)d_in[2];
    const float* w_out = (const float*)d_in[3];
    float* out = (float*)d_out;

    char* ws = (char*)d_ws;
    unsigned short* xb     = (unsigned short*)(ws);                 // [4096][1024] bf16
    unsigned short* wqkvT  = (unsigned short*)(ws + (8u  << 20));   // [3072][1024] bf16
    unsigned short* woutT  = (unsigned short*)(ws + (14u << 20));   // [1024][1024] bf16
    unsigned short* qkvb   = (unsigned short*)(ws + (16u << 20));   // [4096][3072] (Q,K; Q prescaled)
    unsigned short* attnb  = (unsigned short*)(ws + (48u << 20));   // [4096][1024] bf16
    unsigned short* vT     = (unsigned short*)(ws + (56u << 20));   // [1024][4096] bf16

    prep<<<2048, 256, 0, stream>>>(x, xb, w_qkv, wqkvT, w_out, woutT);

    // qkv = x @ w_qkv ; Q (prescaled), K -> qkvb bf16, V -> vT transposed
    gemm_qkv<<<dim3(192), 1024, 0, stream>>>(xb, wqkvT, qkvb, vT);

    attn_mfma<<<dim3(S_LEN / 64, NH), 256, 0, stream>>>(qkvb, vT, attnb);

    // out = attn @ w_out -> f32 (BN=64: 512 blocks = 2/CU)
    gemm_bt<0, 64><<<dim3(EMB / 64, S_LEN / 128), 256, 0, stream>>>(
        attnb, woutT, out, nullptr, S_LEN, EMB, EMB);
}